// Round 9
// baseline (128.805 us; speedup 1.0000x reference)
//
#include <hip/hip_runtime.h>
#include <math.h>

#define B 64
#define N 2000
#define R 64
#define EMBED 512
#define LABELS 20

#define NM 23   // moments S_0..S_22 per batch
#define NK 22   // exp-series terms

#define KS 25   // k-splits (gf)
#define KC 80   // k-chunk (25*80 = 2000 exactly)

// ws layout (floats):
#define SC_OFF 0                         // A, C2
#define S_OFF 64                         // S[NM][64]
#define FT_OFF 2048                      // fT[N][64]
#define MIX_OFF (FT_OFF + N * B)         // mixT[N][64]
#define HID_OFF (MIX_OFF + N * B)        // hidden[EMBED][64]
#define PGF_OFF (HID_OFF + EMBED * B)    // Pgf[KS][N][64]    (12.8 MB)

__constant__ float c_invfact[NK] = {
    1.0f, 1.0f, 0.5f,
    1.6666666666666666e-01f, 4.1666666666666664e-02f, 8.3333333333333332e-03f,
    1.3888888888888889e-03f, 1.9841269841269841e-04f, 2.4801587301587302e-05f,
    2.7557319223985893e-06f, 2.7557319223985894e-07f, 2.5052108385441720e-08f,
    2.0876756987868100e-09f, 1.6059043836821616e-10f, 1.1470745597729726e-11f,
    7.6471637318198170e-13f, 4.7794773323873860e-14f, 2.8114572543455206e-15f,
    1.5619206968586225e-16f, 8.2206352466243300e-18f, 4.1103176233121650e-19f,
    1.9572941063391263e-20f,
};

// ---------------- kernel 1 (fused): moments | scalars | transpose ----------------
// bid 0..63: per-batch power sums (f64). bid 64: A, C2. bid 65..96: fT tiles.
__global__ __launch_bounds__(256) void prep_fused(const float* __restrict__ f,
                                                  const float* __restrict__ tw,
                                                  const float* __restrict__ tb,
                                                  const float* __restrict__ pw,
                                                  float* __restrict__ sc,
                                                  float* __restrict__ S,
                                                  float* __restrict__ fT) {
    __shared__ float tile[64][65];
    __shared__ double sred[4][NM];
    int bid = blockIdx.x;
    int tid = threadIdx.x;
    if (bid >= 65) {
        int m0 = (bid - 65) * 64;
        int lane = tid & 63, w = tid >> 6;
        for (int bb = w; bb < 64; bb += 4)
            tile[lane][bb] = (m0 + lane < N) ? f[(size_t)bb * N + m0 + lane] : 0.f;
        __syncthreads();
        for (int mm = w; mm < 64; mm += 4)
            if (m0 + mm < N) fT[(size_t)(m0 + mm) * 64 + lane] = tile[mm][lane];
        return;
    }
    if (bid == 64) {
        if (tid < R) {
            float a = tw[tid] * pw[tid];
            float c = tb[tid] * pw[tid];
            for (int off = 32; off; off >>= 1) {
                a += __shfl_down(a, off);
                c += __shfl_down(c, off);
            }
            if (tid == 0) { sc[0] = a; sc[1] = c; }
        }
        return;
    }
    const float* fb = f + (size_t)bid * N;
    double acc[NM];
#pragma unroll
    for (int k = 0; k < NM; ++k) acc[k] = 0.0;
    for (int m = tid; m < N; m += 256) {
        double x = (double)fb[m];
        double p = 1.0;
#pragma unroll
        for (int k = 0; k < NM; ++k) { acc[k] += p; p *= x; }
    }
    for (int off = 32; off; off >>= 1) {
#pragma unroll
        for (int k = 0; k < NM; ++k) acc[k] += __shfl_down(acc[k], off);
    }
    int w = tid >> 6, lane = tid & 63;
    if (lane == 0) {
#pragma unroll
        for (int k = 0; k < NM; ++k) sred[w][k] = acc[k];
    }
    __syncthreads();
    if (tid < NM) {
        double s = sred[0][tid] + sred[1][tid] + sred[2][tid] + sred[3][tid];
        S[tid * 64 + bid] = (float)s;
    }
}

// ---------------- scalar-operand split-K GEMM (gf) ----------------
// P[ks][row][b] = sum_{k in chunk ks} G[row][k] * fT[k][b]
// 256 thr = 4 waves, 8 rows/wave. G loads wave-uniform (scalar path),
// fT slice in VGPRs (coalesced). No LDS, no barriers.
__global__ __launch_bounds__(256) void gemm_gf(const float* __restrict__ A,
                                               const float* __restrict__ X,
                                               float* __restrict__ P) {
    int tid = threadIdx.x;
    int lane = tid & 63;
    int w = __builtin_amdgcn_readfirstlane(tid >> 6);   // 0..3
    int ks = blockIdx.x % KS;
    int nt = blockIdx.x / KS;
    int k0 = ks * KC;
    int row0 = nt * 32 + w * 8;

    float vf[KC];
#pragma unroll
    for (int j = 0; j < KC; ++j) vf[j] = X[(size_t)(k0 + j) * 64 + lane];

    int rowc[8];
#pragma unroll
    for (int r = 0; r < 8; ++r) rowc[r] = (row0 + r < N) ? (row0 + r) : (N - 1);

    float acc[8];
#pragma unroll
    for (int r = 0; r < 8; ++r) acc[r] = 0.f;

#pragma unroll
    for (int j4 = 0; j4 < KC / 4; ++j4) {
        float4 g[8];
#pragma unroll
        for (int r = 0; r < 8; ++r)
            g[r] = *(const float4*)(A + (size_t)rowc[r] * N + k0 + 4 * j4);
#pragma unroll
        for (int r = 0; r < 8; ++r) {
            acc[r] = fmaf(g[r].x, vf[4 * j4 + 0], acc[r]);
            acc[r] = fmaf(g[r].y, vf[4 * j4 + 1], acc[r]);
            acc[r] = fmaf(g[r].z, vf[4 * j4 + 2], acc[r]);
            acc[r] = fmaf(g[r].w, vf[4 * j4 + 3], acc[r]);
        }
    }
#pragma unroll
    for (int r = 0; r < 8; ++r) {
        int row = row0 + r;
        if (row < N) P[((size_t)ks * N + row) * 64 + lane] = acc[r];
    }
}

// ---------------- reduce gf partials + softmax-poly + relu + residual ----------------
__global__ __launch_bounds__(256) void reduce_gf(const float* __restrict__ P,
                                                 const float* __restrict__ fT,
                                                 const float* __restrict__ sc,
                                                 const float* __restrict__ S,
                                                 float* __restrict__ mixT) {
    int flat = blockIdx.x * 256 + threadIdx.x;   // 0..127999
    int b = flat & 63;
    float s = 0.f;
#pragma unroll
    for (int k = 0; k < KS; ++k) s += P[(size_t)k * N * 64 + flat];
    float fn = fT[flat];                         // fT[n][b], flat = n*64+b
    float A = sc[0], C2 = sc[1];
    float t = fmaf(A, fn, C2);
    float Z = 0.f, Wv = 0.f, tp = 1.f;
#pragma unroll
    for (int k = 0; k < NK; ++k) {
        float c = tp * c_invfact[k];
        Z = fmaf(c, S[k * 64 + b], Z);
        Wv = fmaf(c, S[(k + 1) * 64 + b], Wv);
        tp *= t;
    }
    float r = fmaxf(s + Wv / Z, 0.f);
    mixT[flat] = r + fn;
}

// ---------------- fc1 full-K + tanh (fused, no partials) ----------------
// hidden[e][b] = tanh(sum_k w1[e][k]*mixT[k][b] + b1[e])
// 256 blocks x 256 thr; block: 2 e-rows; wave w covers k in [w*500,(w+1)*500).
// w1 loads wave-uniform float4; mixT loads coalesced (256 B/wave, L2-resident).
__global__ __launch_bounds__(256) void fc1_full(const float* __restrict__ mixT,
                                                const float* __restrict__ w1,
                                                const float* __restrict__ b1,
                                                float* __restrict__ hidden) {
    int tid = threadIdx.x;
    int lane = tid & 63;
    int w = __builtin_amdgcn_readfirstlane(tid >> 6);   // 0..3
    int e0 = blockIdx.x * 2;
    int kbeg = w * (N / 4);   // 500
    const float* mt = mixT + (size_t)kbeg * 64 + lane;
    const float4* W0 = (const float4*)(w1 + (size_t)e0 * N + kbeg);
    const float4* W1 = (const float4*)(w1 + (size_t)(e0 + 1) * N + kbeg);
    float a0 = 0.f, a1 = 0.f;
#pragma unroll 5
    for (int i = 0; i < 125; ++i) {
        float4 g0 = W0[i];
        float4 g1 = W1[i];
        float f0 = mt[(4 * i + 0) * 64];
        float f1 = mt[(4 * i + 1) * 64];
        float f2 = mt[(4 * i + 2) * 64];
        float f3 = mt[(4 * i + 3) * 64];
        a0 = fmaf(g0.x, f0, a0); a0 = fmaf(g0.y, f1, a0);
        a0 = fmaf(g0.z, f2, a0); a0 = fmaf(g0.w, f3, a0);
        a1 = fmaf(g1.x, f0, a1); a1 = fmaf(g1.y, f1, a1);
        a1 = fmaf(g1.z, f2, a1); a1 = fmaf(g1.w, f3, a1);
    }
    __shared__ float part[4][2][64];
    part[w][0][lane] = a0;
    part[w][1][lane] = a1;
    __syncthreads();
    if (w < 2) {
        float s = part[0][w][lane] + part[1][w][lane] +
                  part[2][w][lane] + part[3][w][lane];
        hidden[(size_t)(e0 + w) * 64 + lane] = tanhf(s + b1[e0 + w]);
    }
}

// ---------------- logits ----------------
__global__ __launch_bounds__(256) void fc2_kernel(const float* __restrict__ hidden,
                                                  const float* __restrict__ w2,
                                                  const float* __restrict__ b2,
                                                  float* __restrict__ out) {
    int l = blockIdx.x;
    int tid = threadIdx.x;
    int lane = tid & 63;
    int w = tid >> 6;
    const float4* W = (const float4*)(w2 + (size_t)l * EMBED) + w * 32;
    const float* h = hidden + (size_t)(w * 128) * B + lane;
    float a0 = 0.f, a1 = 0.f, a2 = 0.f, a3 = 0.f;
#pragma unroll 4
    for (int i = 0; i < 32; ++i) {
        float4 g = W[i];
        a0 = fmaf(g.x, h[(4 * i + 0) * B], a0);
        a1 = fmaf(g.y, h[(4 * i + 1) * B], a1);
        a2 = fmaf(g.z, h[(4 * i + 2) * B], a2);
        a3 = fmaf(g.w, h[(4 * i + 3) * B], a3);
    }
    __shared__ float part[4][64];
    part[w][lane] = (a0 + a1) + (a2 + a3);
    __syncthreads();
    if (w == 0) {
        out[(size_t)lane * LABELS + l] =
            part[0][lane] + part[1][lane] + part[2][lane] + part[3][lane] + b2[l];
    }
}

extern "C" void kernel_launch(void* const* d_in, const int* in_sizes, int n_in,
                              void* d_out, int out_size, void* d_ws, size_t ws_size,
                              hipStream_t stream) {
    const float* feature = (const float*)d_in[0];
    const float* init_graph = (const float*)d_in[1];
    const float* theta_w = (const float*)d_in[2];
    const float* theta_b = (const float*)d_in[3];
    const float* phi_w = (const float*)d_in[4];
    const float* fc1_w = (const float*)d_in[6];
    const float* fc1_b = (const float*)d_in[7];
    const float* fc2_w = (const float*)d_in[8];
    const float* fc2_b = (const float*)d_in[9];
    float* out = (float*)d_out;

    float* ws = (float*)d_ws;
    float* sc = ws + SC_OFF;
    float* S = ws + S_OFF;
    float* fT = ws + FT_OFF;
    float* mixT = ws + MIX_OFF;
    float* hidden = ws + HID_OFF;
    float* Pgf = ws + PGF_OFF;

    // moments + scalars + transpose, fused (97 blocks)
    hipLaunchKernelGGL(prep_fused, dim3(65 + (N + 63) / 64), dim3(256), 0, stream,
                       feature, theta_w, theta_b, phi_w, sc, S, fT);
    // gf: G[2000][2000] x fT -> Pgf   (63 row-tiles x 25 k-splits)
    hipLaunchKernelGGL(gemm_gf, dim3(63 * KS), dim3(256), 0, stream,
                       init_graph, fT, Pgf);
    hipLaunchKernelGGL(reduce_gf, dim3(N * B / 256), dim3(256), 0, stream,
                       Pgf, fT, sc, S, mixT);
    // fc1 full-K fused with tanh (256 blocks, no partial buffer)
    hipLaunchKernelGGL(fc1_full, dim3(EMBED / 2), dim3(256), 0, stream,
                       mixT, fc1_w, fc1_b, hidden);
    hipLaunchKernelGGL(fc2_kernel, dim3(LABELS), dim3(256), 0, stream,
                       hidden, fc2_w, fc2_b, out);
}

// Round 13
// 126.813 us; speedup vs baseline: 1.0157x; 1.0157x over previous
//
#include <hip/hip_runtime.h>
#include <math.h>

#define B 64
#define N 2000
#define R 64
#define EMBED 512
#define LABELS 20

#define NM 23   // moments S_0..S_22 per batch
#define NK 22   // exp-series terms

#define KS 25   // k-splits
#define KC 80   // k-chunk (25*80 = 2000 exactly)

// padded partial-slice strides (break 512KB power-of-two stride channel camping)
#define PSLICE (N * B + 256)       // gf partial slice stride (floats)
#define ESLICE (EMBED * B + 256)   // fc1 partial slice stride (floats)

// ws layout (floats):
#define SC_OFF 0                         // A, C2
#define S_OFF 64                         // S[NM][64]
#define FT_OFF 2048                      // fT[N][64]
#define MIX_OFF (FT_OFF + N * B)         // mixT[N][64]
#define HID_OFF (MIX_OFF + N * B)        // hidden[EMBED][64]
#define PGF_OFF (HID_OFF + EMBED * B)    // Pgf[KS][PSLICE]   (~12.8 MB)
#define PFC_OFF (PGF_OFF + KS * PSLICE)  // Pfc[KS][ESLICE]   (~3.3 MB)

__constant__ float c_invfact[NK] = {
    1.0f, 1.0f, 0.5f,
    1.6666666666666666e-01f, 4.1666666666666664e-02f, 8.3333333333333332e-03f,
    1.3888888888888889e-03f, 1.9841269841269841e-04f, 2.4801587301587302e-05f,
    2.7557319223985893e-06f, 2.7557319223985894e-07f, 2.5052108385441720e-08f,
    2.0876756987868100e-09f, 1.6059043836821616e-10f, 1.1470745597729726e-11f,
    7.6471637318198170e-13f, 4.7794773323873860e-14f, 2.8114572543455206e-15f,
    1.5619206968586225e-16f, 8.2206352466243300e-18f, 4.1103176233121650e-19f,
    1.9572941063391263e-20f,
};

// ---------------- kernel 1 (fused): moments | scalars | transpose ----------------
// bid 0..63: per-batch power sums (f64). bid 64: A, C2. bid 65..96: fT tiles.
__global__ __launch_bounds__(256) void prep_fused(const float* __restrict__ f,
                                                  const float* __restrict__ tw,
                                                  const float* __restrict__ tb,
                                                  const float* __restrict__ pw,
                                                  float* __restrict__ sc,
                                                  float* __restrict__ S,
                                                  float* __restrict__ fT) {
    __shared__ float tile[64][65];
    __shared__ double sred[4][NM];
    int bid = blockIdx.x;
    int tid = threadIdx.x;
    if (bid >= 65) {
        int m0 = (bid - 65) * 64;
        int lane = tid & 63, w = tid >> 6;
        for (int bb = w; bb < 64; bb += 4)
            tile[lane][bb] = (m0 + lane < N) ? f[(size_t)bb * N + m0 + lane] : 0.f;
        __syncthreads();
        for (int mm = w; mm < 64; mm += 4)
            if (m0 + mm < N) fT[(size_t)(m0 + mm) * 64 + lane] = tile[mm][lane];
        return;
    }
    if (bid == 64) {
        if (tid < R) {
            float a = tw[tid] * pw[tid];
            float c = tb[tid] * pw[tid];
            for (int off = 32; off; off >>= 1) {
                a += __shfl_down(a, off);
                c += __shfl_down(c, off);
            }
            if (tid == 0) { sc[0] = a; sc[1] = c; }
        }
        return;
    }
    const float* fb = f + (size_t)bid * N;
    double acc[NM];
#pragma unroll
    for (int k = 0; k < NM; ++k) acc[k] = 0.0;
    for (int m = tid; m < N; m += 256) {
        double x = (double)fb[m];
        double p = 1.0;
#pragma unroll
        for (int k = 0; k < NM; ++k) { acc[k] += p; p *= x; }
    }
    for (int off = 32; off; off >>= 1) {
#pragma unroll
        for (int k = 0; k < NM; ++k) acc[k] += __shfl_down(acc[k], off);
    }
    int w = tid >> 6, lane = tid & 63;
    if (lane == 0) {
#pragma unroll
        for (int k = 0; k < NM; ++k) sred[w][k] = acc[k];
    }
    __syncthreads();
    if (tid < NM) {
        double s = sred[0][tid] + sred[1][tid] + sred[2][tid] + sred[3][tid];
        S[tid * 64 + bid] = (float)s;
    }
}

// ---------------- scalar-operand split-K GEMM (256 thr = 4 waves, 8 rows/wave) ----
// P[ks*SLICE + row*64 + b] = sum_{k in chunk ks} A[row][k] * X[k][b]
// A values wave-uniform (w readfirstlane'd) -> scalar path; X slice in VGPRs.
template <int M, int SLICE>
__global__ __launch_bounds__(256) void gemm_part(const float* __restrict__ A,
                                                 const float* __restrict__ X,
                                                 float* __restrict__ P) {
    int tid = threadIdx.x;
    int lane = tid & 63;
    int w = __builtin_amdgcn_readfirstlane(tid >> 6);   // 0..3
    int ks = blockIdx.x % KS;
    int nt = blockIdx.x / KS;
    int k0 = ks * KC;
    int row0 = nt * 32 + w * 8;

    float vf[KC];
#pragma unroll
    for (int j = 0; j < KC; ++j) vf[j] = X[(size_t)(k0 + j) * 64 + lane];

    int rowc[8];
#pragma unroll
    for (int r = 0; r < 8; ++r) rowc[r] = (row0 + r < M) ? (row0 + r) : (M - 1);

    float acc[8];
#pragma unroll
    for (int r = 0; r < 8; ++r) acc[r] = 0.f;

#pragma unroll
    for (int j4 = 0; j4 < KC / 4; ++j4) {
        float4 g[8];
#pragma unroll
        for (int r = 0; r < 8; ++r)
            g[r] = *(const float4*)(A + (size_t)rowc[r] * N + k0 + 4 * j4);
#pragma unroll
        for (int r = 0; r < 8; ++r) {
            acc[r] = fmaf(g[r].x, vf[4 * j4 + 0], acc[r]);
            acc[r] = fmaf(g[r].y, vf[4 * j4 + 1], acc[r]);
            acc[r] = fmaf(g[r].z, vf[4 * j4 + 2], acc[r]);
            acc[r] = fmaf(g[r].w, vf[4 * j4 + 3], acc[r]);
        }
    }
#pragma unroll
    for (int r = 0; r < 8; ++r) {
        int row = row0 + r;
        if (row < M) P[(size_t)ks * SLICE + (size_t)row * 64 + lane] = acc[r];
    }
}

// ---------------- reduce gf partials (float4) + softmax-poly + relu + residual ----
// thread owns 4 consecutive flats (same n, b..b+3). 125 blocks x 256.
__global__ __launch_bounds__(256) void reduce_gf(const float* __restrict__ P,
                                                 const float* __restrict__ fT,
                                                 const float* __restrict__ sc,
                                                 const float* __restrict__ S,
                                                 float* __restrict__ mixT) {
    int q = blockIdx.x * 256 + threadIdx.x;      // 0..31999, flat = 4q
    int b0 = (4 * q) & 63;
    float4 s = make_float4(0.f, 0.f, 0.f, 0.f);
#pragma unroll
    for (int k = 0; k < KS; ++k) {
        float4 p = *(const float4*)(P + (size_t)k * PSLICE + 4 * (size_t)q);
        s.x += p.x; s.y += p.y; s.z += p.z; s.w += p.w;
    }
    float4 fn = *(const float4*)(fT + 4 * (size_t)q);
    float Ax = sc[0], C2 = sc[1];
    float rr[4];
    float fnv[4] = {fn.x, fn.y, fn.z, fn.w};
    float sv[4] = {s.x, s.y, s.z, s.w};
#pragma unroll
    for (int c = 0; c < 4; ++c) {
        float t = fmaf(Ax, fnv[c], C2);
        float Z = 0.f, Wv = 0.f, tp = 1.f;
#pragma unroll
        for (int k = 0; k < NK; ++k) {
            float cf = tp * c_invfact[k];
            Z = fmaf(cf, S[k * 64 + b0 + c], Z);
            Wv = fmaf(cf, S[(k + 1) * 64 + b0 + c], Wv);
            tp *= t;
        }
        rr[c] = fmaxf(sv[c] + Wv / Z, 0.f) + fnv[c];
    }
    *(float4*)(mixT + 4 * (size_t)q) = make_float4(rr[0], rr[1], rr[2], rr[3]);
}

// ---------------- reduce fc1 partials (float4) + bias + tanh ----------------
__global__ __launch_bounds__(256) void reduce_fc1(const float* __restrict__ P,
                                                  const float* __restrict__ b1,
                                                  float* __restrict__ hidden) {
    int q = blockIdx.x * 256 + threadIdx.x;      // 0..8191, flat = 4q
    int e = (4 * q) >> 6;
    float4 s = make_float4(0.f, 0.f, 0.f, 0.f);
#pragma unroll
    for (int k = 0; k < KS; ++k) {
        float4 p = *(const float4*)(P + (size_t)k * ESLICE + 4 * (size_t)q);
        s.x += p.x; s.y += p.y; s.z += p.z; s.w += p.w;
    }
    float bb = b1[e];
    s.x = tanhf(s.x + bb);
    s.y = tanhf(s.y + bb);
    s.z = tanhf(s.z + bb);
    s.w = tanhf(s.w + bb);
    *(float4*)(hidden + 4 * (size_t)q) = s;
}

// ---------------- logits ----------------
__global__ __launch_bounds__(256) void fc2_kernel(const float* __restrict__ hidden,
                                                  const float* __restrict__ w2,
                                                  const float* __restrict__ b2,
                                                  float* __restrict__ out) {
    int l = blockIdx.x;
    int tid = threadIdx.x;
    int lane = tid & 63;
    int w = tid >> 6;
    const float4* W = (const float4*)(w2 + (size_t)l * EMBED) + w * 32;
    const float* h = hidden + (size_t)(w * 128) * B + lane;
    float a0 = 0.f, a1 = 0.f, a2 = 0.f, a3 = 0.f;
#pragma unroll 4
    for (int i = 0; i < 32; ++i) {
        float4 g = W[i];
        a0 = fmaf(g.x, h[(4 * i + 0) * B], a0);
        a1 = fmaf(g.y, h[(4 * i + 1) * B], a1);
        a2 = fmaf(g.z, h[(4 * i + 2) * B], a2);
        a3 = fmaf(g.w, h[(4 * i + 3) * B], a3);
    }
    __shared__ float part[4][64];
    part[w][lane] = (a0 + a1) + (a2 + a3);
    __syncthreads();
    if (w == 0) {
        out[(size_t)lane * LABELS + l] =
            part[0][lane] + part[1][lane] + part[2][lane] + part[3][lane] + b2[l];
    }
}

extern "C" void kernel_launch(void* const* d_in, const int* in_sizes, int n_in,
                              void* d_out, int out_size, void* d_ws, size_t ws_size,
                              hipStream_t stream) {
    const float* feature = (const float*)d_in[0];
    const float* init_graph = (const float*)d_in[1];
    const float* theta_w = (const float*)d_in[2];
    const float* theta_b = (const float*)d_in[3];
    const float* phi_w = (const float*)d_in[4];
    const float* fc1_w = (const float*)d_in[6];
    const float* fc1_b = (const float*)d_in[7];
    const float* fc2_w = (const float*)d_in[8];
    const float* fc2_b = (const float*)d_in[9];
    float* out = (float*)d_out;

    float* ws = (float*)d_ws;
    float* sc = ws + SC_OFF;
    float* S = ws + S_OFF;
    float* fT = ws + FT_OFF;
    float* mixT = ws + MIX_OFF;
    float* hidden = ws + HID_OFF;
    float* Pgf = ws + PGF_OFF;
    float* Pfc = ws + PFC_OFF;

    // moments + scalars + transpose, fused (97 blocks)
    hipLaunchKernelGGL(prep_fused, dim3(65 + (N + 63) / 64), dim3(256), 0, stream,
                       feature, theta_w, theta_b, phi_w, sc, S, fT);
    // gf: G[2000][2000] x fT -> Pgf   (63 row-tiles x 25 k-splits)
    hipLaunchKernelGGL((gemm_part<N, PSLICE>), dim3(63 * KS), dim3(256), 0, stream,
                       init_graph, fT, Pgf);
    hipLaunchKernelGGL(reduce_gf, dim3(N * B / 1024), dim3(256), 0, stream,
                       Pgf, fT, sc, S, mixT);
    // fc1: w1[512][2000] x mixT -> Pfc  (16 row-tiles x 25 k-splits)
    hipLaunchKernelGGL((gemm_part<EMBED, ESLICE>), dim3(16 * KS), dim3(256), 0, stream,
                       fc1_w, mixT, Pfc);
    hipLaunchKernelGGL(reduce_fc1, dim3(EMBED * B / 1024), dim3(256), 0, stream,
                       Pfc, fc1_b, hidden);
    hipLaunchKernelGGL(fc2_kernel, dim3(LABELS), dim3(256), 0, stream,
                       hidden, fc2_w, fc2_b, out);
}